// Round 1
// 436.026 us; speedup vs baseline: 1.0182x; 1.0182x over previous
//
#include <hip/hip_runtime.h>
#include <cstdint>
#include <cstddef>

typedef __bf16 bf16;
typedef __bf16 bf16x8 __attribute__((ext_vector_type(8)));
typedef float  f32x4  __attribute__((ext_vector_type(4)));

static_assert(sizeof(bf16x8) == 16, "bf16x8 must be 16B");

// async global->LDS, 16B per lane; lane i's data lands at ldsbase + i*16.
__device__ __forceinline__ void async_copy16(const bf16* g, bf16* l) {
  __builtin_amdgcn_global_load_lds(
      (__attribute__((address_space(1))) void*)(g),
      (__attribute__((address_space(3))) void*)(l),
      16, 0, 0);
}

// fp32 -> bf16 bulk convert, 8 elems/thread. n must be a multiple of 2048.
__global__ __launch_bounds__(256)
void conv_f32_bf16(const float* __restrict__ s, bf16* __restrict__ d) {
  const size_t i = ((size_t)blockIdx.x * 256 + threadIdx.x) * 8;
  const f32x4 a = *(const f32x4*)(s + i);
  const f32x4 b = *(const f32x4*)(s + i + 4);
  bf16x8 o;
#pragma unroll
  for (int e = 0; e < 4; ++e) { o[e] = (bf16)a[e]; o[4 + e] = (bf16)b[e]; }
  *(bf16x8*)(d + i) = o;
}

// C[m,n] = sum_k A[m,k] * W[n,k], all-bf16 m97-style: 128x128 tile, BK=64,
// async global->LDS both operands, XOR chunk swizzle (LDS[row][c]=G[row][c^(row&7)]).
// AMODE 0: A row-major [M,K].  AMODE 2: A gathered from [B,H,S,D] plane (k=h*128+d).
// CMODE 0: C fp32 row-major -> Crow.
// CMODE 1: C scattered bf16; global col = nbase+n: <2048 -> Cq[b,h,s,d],
//          <4096 -> Ck[b,h,s,d], else -> Cvt TRANSPOSED [b,h,d,s].
template<int AMODE, int CMODE>
__global__ __launch_bounds__(256, 2)
void gemm_bt(const bf16* __restrict__ A, const bf16* __restrict__ W,
             float* __restrict__ Crow, bf16* __restrict__ Cq,
             bf16* __restrict__ Ck, bf16* __restrict__ Cvt,
             int M, int N, int K, int nbase) {
  __shared__ bf16 As[128 * 64];
  __shared__ bf16 Ws[128 * 64];

  const int tid  = threadIdx.x;
  const int wave = tid >> 6;
  const int lane = tid & 63;
  const int quad = lane >> 4;
  const int r    = lane & 15;
  const int m0 = blockIdx.y * 128;
  const int n0 = blockIdx.x * 128;
  const int wm = (wave >> 1) * 64;
  const int wn = (wave & 1) * 64;

  const int lrow   = lane >> 3;      // 0..7
  const int gchunk = (lane & 7) ^ lrow;

  f32x4 acc[4][4] = {};

  for (int k0 = 0; k0 < K; k0 += 64) {
    __syncthreads();
    for (int j = 0; j < 4; ++j) {
      const int rbase = (wave * 4 + j) * 8;
      const int rowA  = m0 + rbase + lrow;
      const bf16* aSrc;
      if constexpr (AMODE == 2) {
        const int b = rowA >> 11, s = rowA & 2047;
        aSrc = A + ((size_t)(b * 16 + (k0 >> 7)) * 2048 + s) * 128
                 + (k0 & 127) + gchunk * 8;
      } else {
        aSrc = A + (size_t)rowA * K + k0 + gchunk * 8;
      }
      async_copy16(aSrc, As + rbase * 64);
      async_copy16(W + (size_t)(n0 + rbase + lrow) * K + k0 + gchunk * 8,
                   Ws + rbase * 64);
    }
    __syncthreads();
    for (int ks = 0; ks < 2; ++ks) {
      bf16x8 af[4], bfv[4];
      for (int i = 0; i < 4; ++i) {
        const int ar = wm + i * 16 + r;
        af[i]  = *(const bf16x8*)(As + ar * 64 + (((ks * 4 + quad) ^ (ar & 7)) * 8));
        const int br = wn + i * 16 + r;
        bfv[i] = *(const bf16x8*)(Ws + br * 64 + (((ks * 4 + quad) ^ (br & 7)) * 8));
      }
      for (int i = 0; i < 4; ++i)
        for (int j = 0; j < 4; ++j)
          acc[i][j] = __builtin_amdgcn_mfma_f32_16x16x32_bf16(af[i], bfv[j], acc[i][j], 0, 0, 0);
    }
  }

  // C-layout: row = quad*4+reg, col = lane&15 (m89-verified).
  for (int i = 0; i < 4; ++i) {
    const int growb = m0 + wm + i * 16 + quad * 4;
    for (int j = 0; j < 4; ++j) {
      const int gcol = n0 + wn + j * 16 + r;
      for (int rg = 0; rg < 4; ++rg) {
        const int grow = growb + rg;
        if constexpr (CMODE == 1) {
          const int gc = nbase + gcol;
          const int which = gc >> 11;
          const int h = (gc >> 7) & 15;
          const int d = gc & 127;
          const int b = grow >> 11;
          const int s = grow & 2047;
          const bf16 v = (bf16)acc[i][j][rg];
          if (which == 0)
            Cq[(((size_t)b * 16 + h) * 2048 + s) * 128 + d] = v;
          else if (which == 1)
            Ck[(((size_t)b * 16 + h) * 2048 + s) * 128 + d] = v;
          else
            Cvt[(((size_t)b * 16 + h) * 128 + d) * 2048 + s] = v;  // transposed
        } else {
          Crow[(size_t)grow * N + gcol] = acc[i][j][rg];
        }
      }
    }
  }
}

// Flash attention, causal. Q,K: [B*H, S, 128] bf16; Vt: [B*H, 128, S] bf16
// (pre-transposed). O written IN-PLACE into the Q plane (block-private rows).
//
// Load balance: grid (8, B*H); block i processes the causal-complementary
// q-tile pair {15-i, i} SEQUENTIALLY -> uniform 34 KV-tile loads per block,
// 256 blocks = 1 block/CU (no unlucky heavy-heavy CU pairing).
// Staging: double-buffered global_load_lds (linear LDS dest, pre-swizzled
// global source), counted s_waitcnt vmcnt(8) so next tile's 8 loads stay in
// flight across the barrier (T3 minimum 2-phase + T4).
// T5 setprio around MFMA clusters; T13 defer-max skips the O-rescale when
// per-tile row-max growth <= 8 (log2 units; exact math, P bounded by 2^8).
__global__ __launch_bounds__(256, 2)
void attn_kernel(bf16* __restrict__ Q, const bf16* __restrict__ K,
                 const bf16* __restrict__ Vt, int S) {
  __shared__ bf16 k_lds[2][64 * 128];   // [kv][d], swizzled
  __shared__ bf16 v_lds[2][128 * 64];   // [d][kv], swizzled
  __shared__ bf16 p_lds[4][32 * 64];    // per-wave P [qrow][kv], swizzled

  const int tid = threadIdx.x, wave = tid >> 6, lane = tid & 63;
  const int quad = lane >> 4, r = lane & 15;
  const int bh = blockIdx.y;
  bf16* Qh = Q + (size_t)bh * S * 128;
  const bf16* Kh = K + (size_t)bh * S * 128;
  const bf16* Vth = Vt + (size_t)bh * 128 * S;

  const float sc = 0.0883883476483184f * 1.4426950408889634f; // 1/sqrt(128)*log2e

  // Issue one KV tile's staging: 8 async 16B chunks/thread (4 K + 4 V).
  // LDS dest is linear (wave-uniform base, lane*16 implicit); the XOR chunk
  // swizzle is applied to the GLOBAL source address (rule #21 / m173).
  auto issue_stage = [&](int kv0, int buf) {
#pragma unroll
    for (int j = 0; j < 4; ++j) {
      const int lin0 = j * 256 + wave * 64;       // wave-uniform
      const int lin = lin0 + lane;
      const int row = lin >> 4, ch = lin & 15;    // K: [64 kv][16 chunks]
      async_copy16(Kh + (size_t)(kv0 + row) * 128 + ((ch ^ (row & 7)) << 3),
                   &k_lds[buf][0] + lin0 * 8);
    }
#pragma unroll
    for (int j = 0; j < 4; ++j) {
      const int lin0 = j * 256 + wave * 64;
      const int lin = lin0 + lane;
      const int row = lin >> 3, c = lin & 7;      // V^T: [128 d][8 chunks]
      async_copy16(Vth + (size_t)row * S + kv0 + ((c ^ (row & 7)) << 3),
                   &v_lds[buf][0] + lin0 * 8);
    }
  };

  for (int pass = 0; pass < 2; ++pass) {
    const int qb = pass ? blockIdx.x : (15 - blockIdx.x);  // heavy tile first
    const int q0 = qb << 7;
    const int qrow0 = q0 + wave * 32;
    const int nkv = (q0 + 128) >> 6;

    // Q fragments in registers: A[m=lane&15][k=quad*8+j] per 32-k step
    bf16x8 qf[2][4];
    for (int mt = 0; mt < 2; ++mt)
      for (int ks = 0; ks < 4; ++ks)
        qf[mt][ks] = *(const bf16x8*)(Qh + (size_t)(qrow0 + mt * 16 + r) * 128 + ks * 32 + quad * 8);

    f32x4 o_acc[2][8] = {};
    f32x4 m_run[2], l_run[2];
    for (int mt = 0; mt < 2; ++mt)
      for (int t = 0; t < 4; ++t) { m_run[mt][t] = -1e30f; l_run[mt][t] = 0.f; }

    issue_stage(0, 0);  // prologue: tile 0 -> buf 0 (prev pass's LDS reads
                        // are fenced by its trailing __syncthreads)

    for (int kt = 0; kt < nkv; ++kt) {
      const int kv0 = kt << 6;
      const int cur = kt & 1;
      if (kt + 1 < nkv) {
        issue_stage((kt + 1) << 6, cur ^ 1);
        // wait current tile (8 newest = next tile stay in flight)
        asm volatile("s_waitcnt vmcnt(8)" ::: "memory");
      } else {
        asm volatile("s_waitcnt vmcnt(0)" ::: "memory");
      }
      __builtin_amdgcn_sched_barrier(0);
      __syncthreads();

      if (kv0 <= qrow0 + 31) {  // tile not fully masked for this wave
        // S = Q K^T
        f32x4 sa[2][4] = {};
        __builtin_amdgcn_s_setprio(1);
        for (int ks = 0; ks < 4; ++ks) {
          bf16x8 kf[4];
          for (int nt = 0; nt < 4; ++nt) {
            const int kr = nt * 16 + r;
            kf[nt] = *(const bf16x8*)(&k_lds[cur][0] + kr * 128 + (((ks * 4 + quad) ^ (kr & 7)) << 3));
          }
          for (int mt = 0; mt < 2; ++mt)
            for (int nt = 0; nt < 4; ++nt)
              sa[mt][nt] = __builtin_amdgcn_mfma_f32_16x16x32_bf16(qf[mt][ks], kf[nt], sa[mt][nt], 0, 0, 0);
        }
        __builtin_amdgcn_s_setprio(0);
        // causal mask on diagonal tiles
        if (kv0 + 63 > qrow0) {
          for (int mt = 0; mt < 2; ++mt)
            for (int nt = 0; nt < 4; ++nt) {
              const int col  = kv0 + nt * 16 + r;
              const int rowb = qrow0 + mt * 16 + quad * 4;
              for (int rg = 0; rg < 4; ++rg)
                if (col > rowb + rg) sa[mt][nt][rg] = -1e30f;
            }
        }
        // online softmax (each score row lives on the 16 lanes of one quad)
        for (int mt = 0; mt < 2; ++mt) {
          f32x4 mx = sa[mt][0];
          for (int nt = 1; nt < 4; ++nt)
            for (int rg = 0; rg < 4; ++rg) mx[rg] = fmaxf(mx[rg], sa[mt][nt][rg]);
          for (int off = 1; off < 16; off <<= 1)
            for (int rg = 0; rg < 4; ++rg) mx[rg] = fmaxf(mx[rg], __shfl_xor(mx[rg], off, 64));
          // T13 defer-max: rescale only when growth is material (P <= 2^8).
          float need = mx[0] - m_run[mt][0];
          for (int rg = 1; rg < 4; ++rg) need = fmaxf(need, mx[rg] - m_run[mt][rg]);
          if (need * sc > 8.0f) {
            f32x4 alpha;
            for (int rg = 0; rg < 4; ++rg) {
              const float mnew = fmaxf(m_run[mt][rg], mx[rg]);
              alpha[rg] = exp2f((m_run[mt][rg] - mnew) * sc);
              m_run[mt][rg] = mnew;
              l_run[mt][rg] *= alpha[rg];
            }
            for (int nt2 = 0; nt2 < 8; ++nt2)
              for (int rg = 0; rg < 4; ++rg) o_acc[mt][nt2][rg] *= alpha[rg];
          }
          f32x4 rsum = {0.f, 0.f, 0.f, 0.f};
          for (int nt = 0; nt < 4; ++nt)
            for (int rg = 0; rg < 4; ++rg) {
              const float p = exp2f((sa[mt][nt][rg] - m_run[mt][rg]) * sc);
              sa[mt][nt][rg] = p;
              rsum[rg] += p;
            }
          for (int off = 1; off < 16; off <<= 1)
            for (int rg = 0; rg < 4; ++rg) rsum[rg] += __shfl_xor(rsum[rg], off, 64);
          for (int rg = 0; rg < 4; ++rg) l_run[mt][rg] += rsum[rg];
          // P: C-layout -> A-layout via per-wave LDS round-trip, swizzled
          for (int nt = 0; nt < 4; ++nt)
            for (int rg = 0; rg < 4; ++rg) {
              const int prow = mt * 16 + quad * 4 + rg;
              const int pcol = nt * 16 + r;
              p_lds[wave][prow * 64 + (((pcol >> 3) ^ (prow & 7)) * 8) + (pcol & 7)] =
                  (bf16)sa[mt][nt][rg];
            }
        }
        // O += P V
        __builtin_amdgcn_s_setprio(1);
        for (int ks2 = 0; ks2 < 2; ++ks2) {
          bf16x8 pf[2];
          for (int mt = 0; mt < 2; ++mt) {
            const int prow = mt * 16 + r;
            pf[mt] = *(const bf16x8*)(p_lds[wave] + prow * 64 + (((ks2 * 4 + quad) ^ (prow & 7)) * 8));
          }
          for (int nt2 = 0; nt2 < 8; ++nt2) {
            const int vrow = nt2 * 16 + r;
            const bf16x8 vf = *(const bf16x8*)(&v_lds[cur][0] + vrow * 64 + (((ks2 * 4 + quad) ^ (vrow & 7)) * 8));
            for (int mt = 0; mt < 2; ++mt)
              o_acc[mt][nt2] = __builtin_amdgcn_mfma_f32_16x16x32_bf16(pf[mt], vf, o_acc[mt][nt2], 0, 0, 0);
          }
        }
        __builtin_amdgcn_s_setprio(0);
      }
      __syncthreads();
    }

    // epilogue: write O back into the Q plane, same [b,h,s,d] coords
    for (int mt = 0; mt < 2; ++mt) {
      f32x4 inv;
      for (int rg = 0; rg < 4; ++rg) inv[rg] = 1.0f / l_run[mt][rg];
      for (int nt2 = 0; nt2 < 8; ++nt2) {
        const int d = nt2 * 16 + r;
        for (int rg = 0; rg < 4; ++rg) {
          const int s = qrow0 + mt * 16 + quad * 4 + rg;
          Qh[(size_t)s * 128 + d] = (bf16)(o_acc[mt][nt2][rg] * inv[rg]);
        }
      }
    }
  }
}

extern "C" void kernel_launch(void* const* d_in, const int* in_sizes, int n_in,
                              void* d_out, int out_size, void* d_ws, size_t ws_size,
                              hipStream_t stream) {
  const float* x     = (const float*)d_in[0];   // [2,2048,2048] fp32
  const float* Wqkv  = (const float*)d_in[1];   // [6144,2048] fp32
  const float* Wproj = (const float*)d_in[2];   // [2048,2048] fp32
  float* out = (float*)d_out;                   // [2,2048,2048] fp32 = 32 MiB

  const int Bm = 4096, E = 2048;
  const size_t plane = 8388608;                 // 16 MiB as bf16

  // ws (48 MiB): [0,plane) Q plane; [plane,2p) V^T plane; [2p,3p) xb then Wproj_bf16.
  // d_out (32 MiB): [0,plane) bf16 K plane; [plane,+6291456) bf16 Wqkv half;
  //   both dead before proj GEMM overwrites d_out with fp32 output.
  bf16* qw  = (bf16*)d_ws;
  bf16* vtw = qw + plane;
  bf16* xb  = vtw + plane;       // later reused for Wproj bf16
  bf16* kw  = (bf16*)d_out;
  bf16* wqb = kw + plane;        // 6291456 elems = 12 MiB, fits in d_out upper half

  // 1) x -> bf16
  conv_f32_bf16<<<8388608 / 2048, 256, 0, stream>>>(x, xb);
  // 2) Wqkv rows [0,3072) -> bf16
  conv_f32_bf16<<<6291456 / 2048, 256, 0, stream>>>(Wqkv, wqb);
  // 3) QKV GEMM chunk A: n in [0,3072) -> all Q + K heads 0..7
  gemm_bt<0, 1><<<dim3(3072 / 128, Bm / 128), 256, 0, stream>>>(
      xb, wqb, nullptr, qw, kw, vtw, Bm, 3072, E, 0);
  // 4) Wqkv rows [3072,6144) -> bf16 (overwrites wqb after chunk A)
  conv_f32_bf16<<<6291456 / 2048, 256, 0, stream>>>(Wqkv + 6291456, wqb);
  // 5) QKV GEMM chunk B: n in [3072,6144) -> K heads 8..15 + all V (transposed)
  gemm_bt<0, 1><<<dim3(3072 / 128, Bm / 128), 256, 0, stream>>>(
      xb, wqb, nullptr, qw, kw, vtw, Bm, 3072, E, 3072);
  // 6) attention (O overwrites Q plane); paired causal blocks, 256 blocks = 1/CU
  attn_kernel<<<dim3(8, 32), 256, 0, stream>>>(qw, kw, vtw, 2048);
  // 7) Wproj -> bf16 (xb region; xb dead)
  conv_f32_bf16<<<4194304 / 2048, 256, 0, stream>>>(Wproj, xb);
  // 8) proj GEMM: A = O plane (gather), C = d_out fp32
  gemm_bt<2, 0><<<dim3(2048 / 128, Bm / 128), 256, 0, stream>>>(
      qw, xb, out, nullptr, nullptr, nullptr, Bm, 2048, E, 0);
}

// Round 2
// 412.475 us; speedup vs baseline: 1.0764x; 1.0571x over previous
//
#include <hip/hip_runtime.h>
#include <cstdint>
#include <cstddef>

typedef __bf16 bf16;
typedef __bf16 bf16x8 __attribute__((ext_vector_type(8)));
typedef float  f32x4  __attribute__((ext_vector_type(4)));

static_assert(sizeof(bf16x8) == 16, "bf16x8 must be 16B");

// async global->LDS, 16B per lane; lane i's data lands at ldsbase + i*16.
__device__ __forceinline__ void async_copy16(const bf16* g, bf16* l) {
  __builtin_amdgcn_global_load_lds(
      (__attribute__((address_space(1))) void*)(g),
      (__attribute__((address_space(3))) void*)(l),
      16, 0, 0);
}

// fp32 -> bf16 bulk convert, 8 elems/thread. n must be a multiple of 2048.
__global__ __launch_bounds__(256)
void conv_f32_bf16(const float* __restrict__ s, bf16* __restrict__ d) {
  const size_t i = ((size_t)blockIdx.x * 256 + threadIdx.x) * 8;
  const f32x4 a = *(const f32x4*)(s + i);
  const f32x4 b = *(const f32x4*)(s + i + 4);
  bf16x8 o;
#pragma unroll
  for (int e = 0; e < 4; ++e) { o[e] = (bf16)a[e]; o[4 + e] = (bf16)b[e]; }
  *(bf16x8*)(d + i) = o;
}

// C[m,n] = sum_k A[m,k] * W[n,k], all-bf16 m97-style: 128x128 tile, BK=64,
// async global->LDS both operands, XOR chunk swizzle (LDS[row][c]=G[row][c^(row&7)]).
// AMODE 0: A row-major [M,K].  AMODE 2: A gathered from [B,H,S,D] plane (k=h*128+d).
// CMODE 0: C fp32 row-major -> Crow.
// CMODE 1: C scattered bf16; global col = nbase+n: <2048 -> Cq[b,h,s,d],
//          <4096 -> Ck[b,h,s,d], else -> Cvt TRANSPOSED [b,h,d,s].
template<int AMODE, int CMODE>
__global__ __launch_bounds__(256, 2)
void gemm_bt(const bf16* __restrict__ A, const bf16* __restrict__ W,
             float* __restrict__ Crow, bf16* __restrict__ Cq,
             bf16* __restrict__ Ck, bf16* __restrict__ Cvt,
             int M, int N, int K, int nbase) {
  __shared__ bf16 As[128 * 64];
  __shared__ bf16 Ws[128 * 64];

  const int tid  = threadIdx.x;
  const int wave = tid >> 6;
  const int lane = tid & 63;
  const int quad = lane >> 4;
  const int r    = lane & 15;
  const int m0 = blockIdx.y * 128;
  const int n0 = blockIdx.x * 128;
  const int wm = (wave >> 1) * 64;
  const int wn = (wave & 1) * 64;

  const int lrow   = lane >> 3;      // 0..7
  const int gchunk = (lane & 7) ^ lrow;

  f32x4 acc[4][4] = {};

  for (int k0 = 0; k0 < K; k0 += 64) {
    __syncthreads();
    for (int j = 0; j < 4; ++j) {
      const int rbase = (wave * 4 + j) * 8;
      const int rowA  = m0 + rbase + lrow;
      const bf16* aSrc;
      if constexpr (AMODE == 2) {
        const int b = rowA >> 11, s = rowA & 2047;
        aSrc = A + ((size_t)(b * 16 + (k0 >> 7)) * 2048 + s) * 128
                 + (k0 & 127) + gchunk * 8;
      } else {
        aSrc = A + (size_t)rowA * K + k0 + gchunk * 8;
      }
      async_copy16(aSrc, As + rbase * 64);
      async_copy16(W + (size_t)(n0 + rbase + lrow) * K + k0 + gchunk * 8,
                   Ws + rbase * 64);
    }
    __syncthreads();
    for (int ks = 0; ks < 2; ++ks) {
      bf16x8 af[4], bfv[4];
      for (int i = 0; i < 4; ++i) {
        const int ar = wm + i * 16 + r;
        af[i]  = *(const bf16x8*)(As + ar * 64 + (((ks * 4 + quad) ^ (ar & 7)) * 8));
        const int br = wn + i * 16 + r;
        bfv[i] = *(const bf16x8*)(Ws + br * 64 + (((ks * 4 + quad) ^ (br & 7)) * 8));
      }
      for (int i = 0; i < 4; ++i)
        for (int j = 0; j < 4; ++j)
          acc[i][j] = __builtin_amdgcn_mfma_f32_16x16x32_bf16(af[i], bfv[j], acc[i][j], 0, 0, 0);
    }
  }

  // C-layout: row = quad*4+reg, col = lane&15 (m89-verified).
  for (int i = 0; i < 4; ++i) {
    const int growb = m0 + wm + i * 16 + quad * 4;
    for (int j = 0; j < 4; ++j) {
      const int gcol = n0 + wn + j * 16 + r;
      for (int rg = 0; rg < 4; ++rg) {
        const int grow = growb + rg;
        if constexpr (CMODE == 1) {
          const int gc = nbase + gcol;
          const int which = gc >> 11;
          const int h = (gc >> 7) & 15;
          const int d = gc & 127;
          const int b = grow >> 11;
          const int s = grow & 2047;
          const bf16 v = (bf16)acc[i][j][rg];
          if (which == 0)
            Cq[(((size_t)b * 16 + h) * 2048 + s) * 128 + d] = v;
          else if (which == 1)
            Ck[(((size_t)b * 16 + h) * 2048 + s) * 128 + d] = v;
          else
            Cvt[(((size_t)b * 16 + h) * 128 + d) * 2048 + s] = v;  // transposed
        } else {
          Crow[(size_t)grow * N + gcol] = acc[i][j][rg];
        }
      }
    }
  }
}

// Flash attention, causal. Q,K: [B*H, S, 128] bf16; Vt: [B*H, 128, S] bf16
// (pre-transposed). O written IN-PLACE into the Q plane (block-private rows).
//
// Load balance: grid (8, B*H); block i processes the causal-complementary
// q-tile pair {15-i, i} SEQUENTIALLY -> uniform 34 KV-tile loads per block.
// Occupancy: 512 threads = 8 waves/block, 256 blocks = 1 block/CU
// -> 2 waves/SIMD so softmax VALU of one wave overlaps MFMA of the other
// (R1 post-mortem: 256-thread blocks left 1 wave/SIMD, zero TLP).
// Each wave owns 16 q-rows.
// Staging: double-buffered global_load_lds (linear LDS dest, pre-swizzled
// global source), counted s_waitcnt vmcnt(4) so next tile's 4 loads/thread
// stay in flight across the barrier (T3 minimum 2-phase + T4).
// T5 setprio around MFMA clusters; T13 defer-max skips the O-rescale when
// per-tile row-max growth <= 8 (log2 units; exact math, P bounded by 2^8).
__global__ __launch_bounds__(512, 2)
void attn_kernel(bf16* __restrict__ Q, const bf16* __restrict__ K,
                 const bf16* __restrict__ Vt, int S) {
  __shared__ bf16 k_lds[2][64 * 128];   // [kv][d], swizzled
  __shared__ bf16 v_lds[2][128 * 64];   // [d][kv], swizzled
  __shared__ bf16 p_lds[8][16 * 64];    // per-wave P [qrow][kv], swizzled

  const int tid = threadIdx.x, wave = tid >> 6, lane = tid & 63;
  const int quad = lane >> 4, r = lane & 15;
  const int bh = blockIdx.y;
  bf16* Qh = Q + (size_t)bh * S * 128;
  const bf16* Kh = K + (size_t)bh * S * 128;
  const bf16* Vth = Vt + (size_t)bh * 128 * S;

  const float sc = 0.0883883476483184f * 1.4426950408889634f; // 1/sqrt(128)*log2e

  // Issue one KV tile's staging: 4 async 16B chunks/thread (2 K + 2 V).
  // LDS dest is linear (wave-uniform base, lane*16 implicit); the XOR chunk
  // swizzle is applied to the GLOBAL source address (rule #21 / m173).
  auto issue_stage = [&](int kv0, int buf) {
#pragma unroll
    for (int j = 0; j < 2; ++j) {
      const int lin0 = j * 512 + wave * 64;       // wave-uniform
      const int lin = lin0 + lane;
      const int row = lin >> 4, ch = lin & 15;    // K: [64 kv][16 chunks]
      async_copy16(Kh + (size_t)(kv0 + row) * 128 + ((ch ^ (row & 7)) << 3),
                   &k_lds[buf][0] + lin0 * 8);
    }
#pragma unroll
    for (int j = 0; j < 2; ++j) {
      const int lin0 = j * 512 + wave * 64;
      const int lin = lin0 + lane;
      const int row = lin >> 3, c = lin & 7;      // V^T: [128 d][8 chunks]
      async_copy16(Vth + (size_t)row * S + kv0 + ((c ^ (row & 7)) << 3),
                   &v_lds[buf][0] + lin0 * 8);
    }
  };

  for (int pass = 0; pass < 2; ++pass) {
    const int qb = pass ? blockIdx.x : (15 - blockIdx.x);  // heavy tile first
    const int q0 = qb << 7;
    const int qrow0 = q0 + wave * 16;   // 16 q-rows per wave
    const int nkv = (q0 + 128) >> 6;

    // Q fragments in registers: A[m=lane&15][k=quad*8+j] per 32-k step
    bf16x8 qf[4];
    for (int ks = 0; ks < 4; ++ks)
      qf[ks] = *(const bf16x8*)(Qh + (size_t)(qrow0 + r) * 128 + ks * 32 + quad * 8);

    f32x4 o_acc[8] = {};
    f32x4 m_run, l_run;
    for (int t = 0; t < 4; ++t) { m_run[t] = -1e30f; l_run[t] = 0.f; }

    issue_stage(0, 0);  // prologue: tile 0 -> buf 0 (prev pass's LDS reads
                        // are fenced by its trailing __syncthreads)

    for (int kt = 0; kt < nkv; ++kt) {
      const int kv0 = kt << 6;
      const int cur = kt & 1;
      if (kt + 1 < nkv) {
        issue_stage((kt + 1) << 6, cur ^ 1);
        // wait current tile (4 newest = next tile stay in flight)
        asm volatile("s_waitcnt vmcnt(4)" ::: "memory");
      } else {
        asm volatile("s_waitcnt vmcnt(0)" ::: "memory");
      }
      __builtin_amdgcn_sched_barrier(0);
      __syncthreads();

      if (kv0 <= qrow0 + 15) {  // tile not fully masked for this wave
        // S = Q K^T
        f32x4 sa[4] = {};
        __builtin_amdgcn_s_setprio(1);
        for (int ks = 0; ks < 4; ++ks) {
          bf16x8 kf[4];
          for (int nt = 0; nt < 4; ++nt) {
            const int kr = nt * 16 + r;
            kf[nt] = *(const bf16x8*)(&k_lds[cur][0] + kr * 128 + (((ks * 4 + quad) ^ (kr & 7)) << 3));
          }
          for (int nt = 0; nt < 4; ++nt)
            sa[nt] = __builtin_amdgcn_mfma_f32_16x16x32_bf16(qf[ks], kf[nt], sa[nt], 0, 0, 0);
        }
        __builtin_amdgcn_s_setprio(0);
        // causal mask on diagonal tiles
        if (kv0 + 63 > qrow0) {
          for (int nt = 0; nt < 4; ++nt) {
            const int col  = kv0 + nt * 16 + r;
            const int rowb = qrow0 + quad * 4;
            for (int rg = 0; rg < 4; ++rg)
              if (col > rowb + rg) sa[nt][rg] = -1e30f;
          }
        }
        // online softmax (each score row lives on the 16 lanes of one quad)
        f32x4 mx = sa[0];
        for (int nt = 1; nt < 4; ++nt)
          for (int rg = 0; rg < 4; ++rg) mx[rg] = fmaxf(mx[rg], sa[nt][rg]);
        for (int off = 1; off < 16; off <<= 1)
          for (int rg = 0; rg < 4; ++rg) mx[rg] = fmaxf(mx[rg], __shfl_xor(mx[rg], off, 64));
        // T13 defer-max: rescale only when growth is material (P <= 2^8).
        float need = mx[0] - m_run[0];
        for (int rg = 1; rg < 4; ++rg) need = fmaxf(need, mx[rg] - m_run[rg]);
        if (need * sc > 8.0f) {
          f32x4 alpha;
          for (int rg = 0; rg < 4; ++rg) {
            const float mnew = fmaxf(m_run[rg], mx[rg]);
            alpha[rg] = exp2f((m_run[rg] - mnew) * sc);
            m_run[rg] = mnew;
            l_run[rg] *= alpha[rg];
          }
          for (int nt2 = 0; nt2 < 8; ++nt2)
            for (int rg = 0; rg < 4; ++rg) o_acc[nt2][rg] *= alpha[rg];
        }
        f32x4 rsum = {0.f, 0.f, 0.f, 0.f};
        for (int nt = 0; nt < 4; ++nt)
          for (int rg = 0; rg < 4; ++rg) {
            const float p = exp2f((sa[nt][rg] - m_run[rg]) * sc);
            sa[nt][rg] = p;
            rsum[rg] += p;
          }
        for (int off = 1; off < 16; off <<= 1)
          for (int rg = 0; rg < 4; ++rg) rsum[rg] += __shfl_xor(rsum[rg], off, 64);
        for (int rg = 0; rg < 4; ++rg) l_run[rg] += rsum[rg];
        // P: C-layout -> A-layout via per-wave LDS round-trip, swizzled
        for (int nt = 0; nt < 4; ++nt)
          for (int rg = 0; rg < 4; ++rg) {
            const int prow = quad * 4 + rg;
            const int pcol = nt * 16 + r;
            p_lds[wave][prow * 64 + (((pcol >> 3) ^ (prow & 7)) * 8) + (pcol & 7)] =
                (bf16)sa[nt][rg];
          }
        // O += P V
        __builtin_amdgcn_s_setprio(1);
        for (int ks2 = 0; ks2 < 2; ++ks2) {
          const int prow = r;
          const bf16x8 pf = *(const bf16x8*)(p_lds[wave] + prow * 64 + (((ks2 * 4 + quad) ^ (prow & 7)) * 8));
          for (int nt2 = 0; nt2 < 8; ++nt2) {
            const int vrow = nt2 * 16 + r;
            const bf16x8 vf = *(const bf16x8*)(&v_lds[cur][0] + vrow * 64 + (((ks2 * 4 + quad) ^ (vrow & 7)) * 8));
            o_acc[nt2] = __builtin_amdgcn_mfma_f32_16x16x32_bf16(pf, vf, o_acc[nt2], 0, 0, 0);
          }
        }
        __builtin_amdgcn_s_setprio(0);
      }
      __syncthreads();
    }

    // epilogue: write O back into the Q plane, same [b,h,s,d] coords
    f32x4 inv;
    for (int rg = 0; rg < 4; ++rg) inv[rg] = 1.0f / l_run[rg];
    for (int nt2 = 0; nt2 < 8; ++nt2) {
      const int d = nt2 * 16 + r;
      for (int rg = 0; rg < 4; ++rg) {
        const int s = qrow0 + quad * 4 + rg;
        Qh[(size_t)s * 128 + d] = (bf16)(o_acc[nt2][rg] * inv[rg]);
      }
    }
  }
}

extern "C" void kernel_launch(void* const* d_in, const int* in_sizes, int n_in,
                              void* d_out, int out_size, void* d_ws, size_t ws_size,
                              hipStream_t stream) {
  const float* x     = (const float*)d_in[0];   // [2,2048,2048] fp32
  const float* Wqkv  = (const float*)d_in[1];   // [6144,2048] fp32
  const float* Wproj = (const float*)d_in[2];   // [2048,2048] fp32
  float* out = (float*)d_out;                   // [2,2048,2048] fp32 = 32 MiB

  const int Bm = 4096, E = 2048;
  const size_t plane = 8388608;                 // 16 MiB as bf16

  // ws (48 MiB): [0,plane) Q plane; [plane,2p) V^T plane; [2p,3p) xb then Wproj_bf16.
  // d_out (32 MiB): [0,plane) bf16 K plane; [plane,+6291456) bf16 Wqkv half;
  //   both dead before proj GEMM overwrites d_out with fp32 output.
  bf16* qw  = (bf16*)d_ws;
  bf16* vtw = qw + plane;
  bf16* xb  = vtw + plane;       // later reused for Wproj bf16
  bf16* kw  = (bf16*)d_out;
  bf16* wqb = kw + plane;        // 6291456 elems = 12 MiB, fits in d_out upper half

  // 1) x -> bf16
  conv_f32_bf16<<<8388608 / 2048, 256, 0, stream>>>(x, xb);
  // 2) Wqkv rows [0,3072) -> bf16
  conv_f32_bf16<<<6291456 / 2048, 256, 0, stream>>>(Wqkv, wqb);
  // 3) QKV GEMM chunk A: n in [0,3072) -> all Q + K heads 0..7
  gemm_bt<0, 1><<<dim3(3072 / 128, Bm / 128), 256, 0, stream>>>(
      xb, wqb, nullptr, qw, kw, vtw, Bm, 3072, E, 0);
  // 4) Wqkv rows [3072,6144) -> bf16 (overwrites wqb after chunk A)
  conv_f32_bf16<<<6291456 / 2048, 256, 0, stream>>>(Wqkv + 6291456, wqb);
  // 5) QKV GEMM chunk B: n in [3072,6144) -> K heads 8..15 + all V (transposed)
  gemm_bt<0, 1><<<dim3(3072 / 128, Bm / 128), 256, 0, stream>>>(
      xb, wqb, nullptr, qw, kw, vtw, Bm, 3072, E, 3072);
  // 6) attention (O overwrites Q plane); paired causal blocks, 8 waves/block
  attn_kernel<<<dim3(8, 32), 512, 0, stream>>>(qw, kw, vtw, 2048);
  // 7) Wproj -> bf16 (xb region; xb dead)
  conv_f32_bf16<<<4194304 / 2048, 256, 0, stream>>>(Wproj, xb);
  // 8) proj GEMM: A = O plane (gather), C = d_out fp32
  gemm_bt<2, 0><<<dim3(2048 / 128, Bm / 128), 256, 0, stream>>>(
      qw, xb, out, nullptr, nullptr, nullptr, Bm, 2048, E, 0);
}